// Round 7
// baseline (832.548 us; speedup 1.0000x reference)
//
#include <hip/hip_runtime.h>

#define SEQ   4096
#define HID   4096
#define EDIM  1024
#define NHEAD 4

typedef __attribute__((ext_vector_type(8))) short short8;
typedef __attribute__((ext_vector_type(16))) float f32x16;

typedef const __attribute__((address_space(1))) void* gas_ptr;
typedef __attribute__((address_space(3))) void* las_ptr;
#define GLD16(g, l) __builtin_amdgcn_global_load_lds((gas_ptr)(g), (las_ptr)(l), 16, 0, 0)

#define BARRIER() __builtin_amdgcn_s_barrier()
#define SCHED0()  __builtin_amdgcn_sched_barrier(0)
#define LGKM0()   asm volatile("s_waitcnt lgkmcnt(0)" ::: "memory")
#define VMC0()    asm volatile("s_waitcnt vmcnt(0)" ::: "memory")

__device__ __forceinline__ unsigned short f2bf(float f) {
  union { float f; unsigned u; } v; v.f = f;
  unsigned r = v.u + 0x7fffu + ((v.u >> 16) & 1u);  // RNE
  return (unsigned short)(r >> 16);
}
__device__ __forceinline__ float bf2f(unsigned short u) {
  union { unsigned u; float f; } v; v.u = ((unsigned)u) << 16;
  return v.f;
}

// packed-B fragment layout (32x32x16 MFMA B-operand order):
//   chunk c = (nt*NKT + kt)*64 + lane ; elem = c*8 + j
//   stores B[col = 32*nt + (lane&31)][k = 16*kt + 8*(lane>>5) + j]
// element (nv, kv) -> nt=nv>>5, kt=kv>>4, lane=(nv&31)+32*((kv>>3)&1), j=kv&7

// ---------------- h: f32 -> bf16 (row-major, GEMM-A operand) ----------------
__global__ __launch_bounds__(256) void hconv_kernel(const float* __restrict__ in,
                                                    unsigned short* __restrict__ out) {
  size_t i = ((size_t)blockIdx.x * 256 + threadIdx.x) * 8;
  const float4 a = *(const float4*)(in + i);
  const float4 b = *(const float4*)(in + i + 4);
  short8 o;
  o[0] = (short)f2bf(a.x); o[1] = (short)f2bf(a.y);
  o[2] = (short)f2bf(a.z); o[3] = (short)f2bf(a.w);
  o[4] = (short)f2bf(b.x); o[5] = (short)f2bf(b.y);
  o[6] = (short)f2bf(b.z); o[7] = (short)f2bf(b.w);
  *(short8*)(out + i) = o;
}

// ---- W [mat][head][D][E] f32 -> packed-B bf16 per (mat,head): nv=e, kv=d, NKT=HID/16 ----
__global__ __launch_bounds__(256) void wconv_kernel(const float* __restrict__ Wq,
                                                    const float* __restrict__ Wk,
                                                    const float* __restrict__ Wv,
                                                    unsigned short* __restrict__ wt) {
  const int mh = blockIdx.y;               // 0..11
  const int mat = mh >> 2, head = mh & 3;
  const float* W = (mat == 0 ? Wq : (mat == 1 ? Wk : Wv)) + (size_t)head * HID * EDIM; // [D][E]
  unsigned short* out = wt + (size_t)mh * EDIM * HID;
  const int tile = blockIdx.x;             // (D/64)*(E/64) = 64*16
  const int td = tile >> 4;                // d-tile 0..63
  const int te = tile & 15;                // e-tile 0..15
  __shared__ float lds[64][65];
  const int tid = threadIdx.x;
  const int r = tid >> 4, c4 = (tid & 15) * 4;
#pragma unroll
  for (int it = 0; it < 4; ++it) {
    int dr = r + 16 * it;
    const float4 v = *(const float4*)&W[(size_t)(td * 64 + dr) * EDIM + te * 64 + c4];
    lds[dr][c4 + 0] = v.x; lds[dr][c4 + 1] = v.y;
    lds[dr][c4 + 2] = v.z; lds[dr][c4 + 3] = v.w;
  }
  __syncthreads();
#pragma unroll
  for (int it = 0; it < 4; ++it) {
    int er = r + 16 * it;
    const int e = te * 64 + er;
    const int d0 = td * 64 + c4;
    ushort4 o;
    o.x = f2bf(lds[c4 + 0][er]); o.y = f2bf(lds[c4 + 1][er]);
    o.z = f2bf(lds[c4 + 2][er]); o.w = f2bf(lds[c4 + 3][er]);
    const size_t ad = (((size_t)(e >> 5) * (HID / 16) + (d0 >> 4)) * 64 +
                       (e & 31) + 32 * ((d0 >> 3) & 1)) * 8 + (d0 & 7);
    *(ushort4*)&out[ad] = o;
  }
}

// ---------------- 256x256 bf16 MFMA GEMM (32x32x16), A via LDS, B DIRECT ----------------
// A [M][K] row-major bf16 (LDS-staged, 64KB dbuf, XOR swizzle). B pre-packed in fragment
// order (see above); loaded global->VGPR, double-buffered one tile ahead (static 2-set
// naming, loop unrolled x2). One barrier + one vmcnt(0) per K-tile (r6 discipline):
// VMC0 -> own A(t) in LDS + bv(t) in regs; BARRIER -> all waves past t-1 reads, safe to
// stage A(t+1) into slot^1 and issue bv(t+1).
// MODE 0: bf16 out [row][col], +bias[col]                          (Q: scores-A)
// MODE 2: bf16 out [row][col], *scale                              (scores)
// MODE 3: f32  out [row][col]                                      (final out)
// MODE 4: packed-B out over (nv=row, kv=col), NKT=EDIM/16, +bias   (K: scores-B)
// MODE 5: packed-B out over (nv=col, kv=row), NKT=SEQ/16,  +bias   (V: PV-B)
template <int MODE>
__global__ __launch_bounds__(512, 2) void gemmBD_kernel(
    const unsigned short* __restrict__ Aall, const unsigned short* __restrict__ Bp,
    long long aBatch, long long bBatch, int K, int NKT,
    const float* __restrict__ biasAll, long long biasBatch,
    void* __restrict__ outAll, long long outBatch, int ldOut, float scale,
    int gx, int gxy) {
  extern __shared__ char smem[];

  // XCD-aware bijective block swizzle (all grids have nwg % 8 == 0)
  const int nwg = (int)gridDim.x;
  const int lin = (int)blockIdx.x;
  int wg = (lin & 7) * (nwg >> 3) + (lin >> 3);
  const int z = wg / gxy; wg -= z * gxy;
  const int by = wg / gx;
  const int bx = wg - by * gx;
  const int bm = by * 256, bn = bx * 256;

  const unsigned short* A = Aall + (size_t)z * aBatch;
  const unsigned short* B = Bp + (size_t)z * bBatch;

  const int tid = threadIdx.x;           // 0..511
  const int lane = tid & 63, wid = tid >> 6;
  const int wr = wid >> 2, wc = wid & 3; // wave -> (2 x 4) output grid
  const int la31 = lane & 31, lg2 = lane >> 5;

  // ---- A staging: 256 rows x 128 B per tile; thread covers rows srow+{0,64,128,192}.
  const int srow = tid >> 3;                                // 0..63
  const int sk = ((tid & 7) ^ ((srow ^ (srow >> 3)) & 7)) * 8;
  const unsigned short* aS0 = A + (size_t)(bm +   0 + srow) * K + sk;
  const unsigned short* aS1 = A + (size_t)(bm +  64 + srow) * K + sk;
  const unsigned short* aS2 = A + (size_t)(bm + 128 + srow) * K + sk;
  const unsigned short* aS3 = A + (size_t)(bm + 192 + srow) * K + sk;

#define STGA(tt)                                                          \
  do {                                                                    \
    char* _d = smem + (((tt) & 1) << 15) + tid * 16;                      \
    GLD16(aS0 + (size_t)(tt) * 64, _d);                                   \
    GLD16(aS1 + (size_t)(tt) * 64, _d + 8192);                            \
    GLD16(aS2 + (size_t)(tt) * 64, _d + 16384);                          \
    GLD16(aS3 + (size_t)(tt) * 64, _d + 24576);                          \
  } while (0)

  // ---- A fragment read bases (row stride 128 B, XOR-swizzled 16B slots)
  int aO[4], aX[4];
#pragma unroll
  for (int m = 0; m < 4; ++m) {
    const int arow = wr * 128 + m * 32 + la31;
    aO[m] = arow * 128;
    aX[m] = (arow ^ (arow >> 3)) & 7;
  }

  // ---- direct-B pointers: wave's n-tiles nt = bn/32 + wc*2 + {0,1}
  const unsigned short* bvP0 = B + ((size_t)((bn >> 5) + wc * 2 + 0) * NKT) * 512 + lane * 8;
  const unsigned short* bvP1 = B + ((size_t)((bn >> 5) + wc * 2 + 1) * NKT) * 512 + lane * 8;

  f32x16 acc[4][2];
#pragma unroll
  for (int m = 0; m < 4; ++m)
#pragma unroll
    for (int n = 0; n < 2; ++n)
#pragma unroll
      for (int r = 0; r < 16; ++r) acc[m][n][r] = 0.f;

  const int NT = K >> 6;    // K-tiles of 64 (always even here)

  short8 bvA[2][4], bvB[2][4], av[2][4];

#define LOADBV(S, tt)                                                     \
  do {                                                                    \
    _Pragma("unroll") for (int ks = 0; ks < 4; ++ks) {                    \
      S[0][ks] = *(const short8*)(bvP0 + (size_t)(tt) * 2048 + ks * 512); \
      S[1][ks] = *(const short8*)(bvP1 + (size_t)(tt) * 2048 + ks * 512); \
    }                                                                     \
  } while (0)

// one K-tile: RD = bv set for this tile, LD = bv set to fill with tile tt+1
#define TILE(tt, RD, LD)                                                  \
  do {                                                                    \
    const char* base = smem + (((tt) & 1) << 15);                         \
    VMC0();                                                               \
    BARRIER();                                                            \
    SCHED0();                                                             \
    if ((tt) + 1 < NT) {                                                  \
      STGA((tt) + 1);                                                     \
      LOADBV(LD, (tt) + 1);                                               \
    }                                                                     \
    _Pragma("unroll") for (int m = 0; m < 2; ++m)                         \
      _Pragma("unroll") for (int ks = 0; ks < 4; ++ks)                    \
        av[m][ks] = *(const short8*)(base + aO[m] +                       \
                                     ((((ks << 1) + lg2) ^ aX[m]) << 4)); \
    LGKM0();                                                              \
    SCHED0();                                                             \
    __builtin_amdgcn_s_setprio(1);                                        \
    _Pragma("unroll") for (int ks = 0; ks < 4; ++ks)                      \
      _Pragma("unroll") for (int m = 0; m < 2; ++m)                       \
        _Pragma("unroll") for (int n = 0; n < 2; ++n)                     \
          acc[m][n] = __builtin_amdgcn_mfma_f32_32x32x16_bf16(            \
              av[m][ks], RD[n][ks], acc[m][n], 0, 0, 0);                  \
    __builtin_amdgcn_s_setprio(0);                                        \
    _Pragma("unroll") for (int m = 0; m < 2; ++m)                         \
      _Pragma("unroll") for (int ks = 0; ks < 4; ++ks)                    \
        av[m][ks] = *(const short8*)(base + aO[m + 2] +                   \
                                     ((((ks << 1) + lg2) ^ aX[m + 2]) << 4)); \
    LGKM0();                                                              \
    SCHED0();                                                             \
    __builtin_amdgcn_s_setprio(1);                                        \
    _Pragma("unroll") for (int ks = 0; ks < 4; ++ks)                      \
      _Pragma("unroll") for (int m = 0; m < 2; ++m)                       \
        _Pragma("unroll") for (int n = 0; n < 2; ++n)                     \
          acc[m + 2][n] = __builtin_amdgcn_mfma_f32_32x32x16_bf16(        \
              av[m][ks], RD[n][ks], acc[m + 2][n], 0, 0, 0);              \
    __builtin_amdgcn_s_setprio(0);                                        \
    SCHED0();                                                             \
  } while (0)

  // ---- prologue: stage A(0), load bv(0) into set A
  STGA(0);
  LOADBV(bvA, 0);

  for (int i = 0; i < (NT >> 1); ++i) {
    TILE(2 * i,     bvA, bvB);
    TILE(2 * i + 1, bvB, bvA);
  }
#undef TILE
#undef LOADBV
#undef STGA

  // ---- epilogue (C/D: col = lane&31, row = (r&3) + 8*(r>>2) + 4*(lane>>5))
  float bvv[2];
  if (MODE == 0 || MODE == 4 || MODE == 5) {
    const float* bias = biasAll + (size_t)z * biasBatch;
#pragma unroll
    for (int n = 0; n < 2; ++n) bvv[n] = bias[bn + wc * 64 + n * 32 + la31];
  }
#pragma unroll
  for (int m = 0; m < 4; ++m)
#pragma unroll
    for (int n = 0; n < 2; ++n)
#pragma unroll
      for (int r = 0; r < 16; ++r) {
        const int grow = bm + wr * 128 + m * 32 + (r & 3) + 8 * (r >> 2) + 4 * lg2;
        const int gcol = bn + wc * 64 + n * 32 + la31;
        float val = acc[m][n][r];
        if (MODE == 0 || MODE == 4 || MODE == 5) val += bvv[n];
        if (MODE == 2) val *= scale;
        if (MODE == 0 || MODE == 2) {
          unsigned short* o = (unsigned short*)outAll + (size_t)z * outBatch;
          o[(size_t)grow * ldOut + gcol] = f2bf(val);
        } else if (MODE == 3) {
          float* o = (float*)outAll + (size_t)z * outBatch;
          o[(size_t)grow * ldOut + gcol] = val;
        } else if (MODE == 4) {
          // packed-B over (nv=grow=t, kv=gcol=e), NKT = EDIM/16 = 64
          unsigned short* o = (unsigned short*)outAll + (size_t)z * outBatch;
          const size_t ad = (((size_t)(grow >> 5) * (EDIM / 16) + (gcol >> 4)) * 64 +
                             (grow & 31) + 32 * ((gcol >> 3) & 1)) * 8 + (gcol & 7);
          o[ad] = f2bf(val);
        } else if (MODE == 5) {
          // packed-B over (nv=gcol=e, kv=grow=t), NKT = SEQ/16 = 256
          unsigned short* o = (unsigned short*)outAll + (size_t)z * outBatch;
          const size_t ad = (((size_t)(gcol >> 5) * (SEQ / 16) + (grow >> 4)) * 64 +
                             (gcol & 31) + 32 * ((grow >> 3) & 1)) * 8 + (grow & 7);
          o[ad] = f2bf(val);
        }
      }
}

// ---------------- row softmax, in place on bf16 [nrows][SEQ] ----------------
__global__ __launch_bounds__(256) void softmax_kernel(unsigned short* __restrict__ Sb) {
  const size_t row = blockIdx.x;
  unsigned short* p = Sb + row * (size_t)SEQ;
  const int tid = threadIdx.x;
  const int lane = tid & 63, wid = tid >> 6;
  float v[16];
  const short8 u0 = *(const short8*)&p[tid * 16];
  const short8 u1 = *(const short8*)&p[tid * 16 + 8];
#pragma unroll
  for (int j = 0; j < 8; ++j) v[j] = bf2f((unsigned short)u0[j]);
#pragma unroll
  for (int j = 0; j < 8; ++j) v[8 + j] = bf2f((unsigned short)u1[j]);
  float mx = v[0];
#pragma unroll
  for (int j = 1; j < 16; ++j) mx = fmaxf(mx, v[j]);
#pragma unroll
  for (int off = 32; off; off >>= 1) mx = fmaxf(mx, __shfl_xor(mx, off));
  __shared__ float red[8];
  if (lane == 0) red[wid] = mx;
  __syncthreads();
  mx = fmaxf(fmaxf(red[0], red[1]), fmaxf(red[2], red[3]));
  float s = 0.f;
#pragma unroll
  for (int j = 0; j < 16; ++j) { v[j] = __expf(v[j] - mx); s += v[j]; }
#pragma unroll
  for (int off = 32; off; off >>= 1) s += __shfl_xor(s, off);
  if (lane == 0) red[4 + wid] = s;
  __syncthreads();
  s = (red[4] + red[5]) + (red[6] + red[7]);
  const float inv = 1.0f / s;
  short8 o0, o1;
#pragma unroll
  for (int j = 0; j < 8; ++j) o0[j] = (short)f2bf(v[j] * inv);
#pragma unroll
  for (int j = 0; j < 8; ++j) o1[j] = (short)f2bf(v[8 + j] * inv);
  *(short8*)&p[tid * 16] = o0;
  *(short8*)&p[tid * 16 + 8] = o1;
}

extern "C" void kernel_launch(void* const* d_in, const int* in_sizes, int n_in,
                              void* d_out, int out_size, void* d_ws, size_t ws_size,
                              hipStream_t stream) {
  const float* h  = (const float*)d_in[0];
  const float* Wq = (const float*)d_in[1];
  const float* bq = (const float*)d_in[2];
  const float* Wk = (const float*)d_in[3];
  const float* bk = (const float*)d_in[4];
  const float* Wv = (const float*)d_in[5];
  const float* bv = (const float*)d_in[6];
  float* out = (float*)d_out;
  char* ws = (char*)d_ws;

  (void)hipFuncSetAttribute((const void*)&gemmBD_kernel<0>,
                            hipFuncAttributeMaxDynamicSharedMemorySize, 65536);
  (void)hipFuncSetAttribute((const void*)&gemmBD_kernel<2>,
                            hipFuncAttributeMaxDynamicSharedMemorySize, 65536);
  (void)hipFuncSetAttribute((const void*)&gemmBD_kernel<3>,
                            hipFuncAttributeMaxDynamicSharedMemorySize, 65536);
  (void)hipFuncSetAttribute((const void*)&gemmBD_kernel<4>,
                            hipFuncAttributeMaxDynamicSharedMemorySize, 65536);
  (void)hipFuncSetAttribute((const void*)&gemmBD_kernel<5>,
                            hipFuncAttributeMaxDynamicSharedMemorySize, 65536);

  // ws layout (224 MB):
  //  [0,32MB)    h_bf16 [S][HID]             -- dead after projections
  //  [32,128MB)  Wt packed-B bf16 [12]       -- dead after projections
  //  [0,128MB)   Sb bf16 [H][S][S]           -- scores/probs (reuses the two above)
  //  [128,160)   Qb bf16 [H][S][E]  row-major (scores-A)
  //  [160,192)   Kb bf16 [H] packed-B        (scores-B)
  //  [192,224)   Vt bf16 [H] packed-B        (PV-B)
  unsigned short* hB = (unsigned short*)ws;
  unsigned short* wt = (unsigned short*)(ws + (32ull << 20));
  unsigned short* Sb = (unsigned short*)ws;
  unsigned short* Qb = (unsigned short*)(ws + (128ull << 20));
  unsigned short* Kb = (unsigned short*)(ws + (160ull << 20));
  unsigned short* Vt = (unsigned short*)(ws + (192ull << 20));

  const long long WED = (long long)EDIM * HID;   // per-(mat,head) Wt elems
  const long long QKB = (long long)SEQ * EDIM;   // per-head Q/K/V elems
  const long long SSB = (long long)SEQ * SEQ;    // per-head score elems

  hconv_kernel<<<dim3((SEQ * (size_t)HID) / (256 * 8)), 256, 0, stream>>>(h, hB);
  wconv_kernel<<<dim3((HID / 64) * (EDIM / 64), 12), 256, 0, stream>>>(Wq, Wk, Wv, wt);

  // Projections: M=S=4096, N=E=1024, K=HID; B = packed Wt (NKT=HID/16=256)
  gemmBD_kernel<0><<<dim3(4 * 16 * 4), 512, 65536, stream>>>(
      hB, wt + 0 * WED, 0, WED, HID, 256, bq, EDIM, Qb, QKB, EDIM, 1.f, 4, 64);
  gemmBD_kernel<4><<<dim3(4 * 16 * 4), 512, 65536, stream>>>(
      hB, wt + 4 * WED, 0, WED, HID, 256, bk, EDIM, Kb, QKB, 0, 1.f, 4, 64);
  gemmBD_kernel<5><<<dim3(4 * 16 * 4), 512, 65536, stream>>>(
      hB, wt + 8 * WED, 0, WED, HID, 256, bv, EDIM, Vt, QKB, 0, 1.f, 4, 64);

  // Scores: S = Q K^T / 32 (M=N=S, K=E); A=Qb row-major, B=Kb packed (NKT=EDIM/16=64)
  gemmBD_kernel<2><<<dim3(16 * 16 * 4), 512, 65536, stream>>>(
      Qb, Kb, QKB, QKB, EDIM, 64, nullptr, 0, Sb, SSB, SEQ, 0.03125f, 16, 256);

  // Softmax over rows, in place
  softmax_kernel<<<dim3(NHEAD * SEQ), 256, 0, stream>>>(Sb);

  // Out: O = P V (M=S, N=E, K=S); A=Sb row-major, B=Vt packed (NKT=SEQ/16=256)
  gemmBD_kernel<3><<<dim3(4 * 16 * 4), 512, 65536, stream>>>(
      Sb, Vt, SSB, QKB, SEQ, 256, nullptr, 0, out, (long long)EDIM, NHEAD * EDIM, 1.f, 4, 64);
}

// Round 8
// 783.323 us; speedup vs baseline: 1.0628x; 1.0628x over previous
//
#include <hip/hip_runtime.h>

#define SEQ   4096
#define HID   4096
#define EDIM  1024
#define NHEAD 4

typedef __attribute__((ext_vector_type(8))) short short8;
typedef __attribute__((ext_vector_type(16))) float f32x16;

typedef const __attribute__((address_space(1))) void* gas_ptr;
typedef __attribute__((address_space(3))) void* las_ptr;
#define GLD16(g, l) __builtin_amdgcn_global_load_lds((gas_ptr)(g), (las_ptr)(l), 16, 0, 0)

#define BARRIER() __builtin_amdgcn_s_barrier()
#define SCHED0()  __builtin_amdgcn_sched_barrier(0)
#define VMC0()    asm volatile("s_waitcnt vmcnt(0)" ::: "memory")

__device__ __forceinline__ unsigned short f2bf(float f) {
  union { float f; unsigned u; } v; v.f = f;
  unsigned r = v.u + 0x7fffu + ((v.u >> 16) & 1u);  // RNE
  return (unsigned short)(r >> 16);
}
__device__ __forceinline__ float bf2f(unsigned short u) {
  union { unsigned u; float f; } v; v.u = ((unsigned)u) << 16;
  return v.f;
}

// ---------------- h: f32 -> bf16 ----------------
__global__ __launch_bounds__(256) void hconv_kernel(const float* __restrict__ in,
                                                    unsigned short* __restrict__ out) {
  size_t i = ((size_t)blockIdx.x * 256 + threadIdx.x) * 8;
  const float4 a = *(const float4*)(in + i);
  const float4 b = *(const float4*)(in + i + 4);
  short8 o;
  o[0] = (short)f2bf(a.x); o[1] = (short)f2bf(a.y);
  o[2] = (short)f2bf(a.z); o[3] = (short)f2bf(a.w);
  o[4] = (short)f2bf(b.x); o[5] = (short)f2bf(b.y);
  o[6] = (short)f2bf(b.z); o[7] = (short)f2bf(b.w);
  *(short8*)(out + i) = o;
}

// ---------------- W [mat][head][D][E] f32 -> Wt [mat*4+head][E][D] bf16 ----------------
__global__ __launch_bounds__(256) void wconv_kernel(const float* __restrict__ Wq,
                                                    const float* __restrict__ Wk,
                                                    const float* __restrict__ Wv,
                                                    unsigned short* __restrict__ wt) {
  const int mh = blockIdx.y;               // 0..11
  const int mat = mh >> 2, head = mh & 3;
  const float* W = (mat == 0 ? Wq : (mat == 1 ? Wk : Wv)) + (size_t)head * HID * EDIM; // [D][E]
  unsigned short* out = wt + (size_t)mh * EDIM * HID;                                  // [E][D]
  const int tile = blockIdx.x;             // (D/64)*(E/64) = 64*16
  const int td = tile >> 4;                // d-tile 0..63
  const int te = tile & 15;                // e-tile 0..15
  __shared__ float lds[64][65];
  const int tid = threadIdx.x;
  const int r = tid >> 4, c4 = (tid & 15) * 4;
#pragma unroll
  for (int it = 0; it < 4; ++it) {
    int dr = r + 16 * it;
    const float4 v = *(const float4*)&W[(size_t)(td * 64 + dr) * EDIM + te * 64 + c4];
    lds[dr][c4 + 0] = v.x; lds[dr][c4 + 1] = v.y;
    lds[dr][c4 + 2] = v.z; lds[dr][c4 + 3] = v.w;
  }
  __syncthreads();
#pragma unroll
  for (int it = 0; it < 4; ++it) {
    int er = r + 16 * it;
    ushort4 o;
    o.x = f2bf(lds[c4 + 0][er]); o.y = f2bf(lds[c4 + 1][er]);
    o.z = f2bf(lds[c4 + 2][er]); o.w = f2bf(lds[c4 + 3][er]);
    *(ushort4*)&out[(size_t)(te * 64 + er) * HID + td * 64 + c4] = o;
  }
}

// ---------------- 256x256 slice-pipelined bf16 MFMA GEMM (32x32x16) ----------------
// C = A * Bt^T. A [M][K] row-major, Bt [N][K] row-major. BK=64, 8 waves (2Mx4N),
// wave out 128x64 = 4x2 tiles of 32x32 (acc f32x16[4][2] = 128 AGPR).
// K-tile = 4 slices of K=16. ONE-SLICE-AHEAD fragment pipeline: phase p issues the
// ds_reads for slice p+1 (into the alternate 24-VGPR set) and MFMAs slice p, so the
// LDS port runs concurrently with the matrix pipe instead of serializing.
// Ring-2 LDS (2 x 64KB). Tile t: ph0 {STG(t+1)->slot(t-1) [dead: all its reads were
// consumed before last barrier], rd slice1, MFMA slice0}; ph1/ph2 likewise; ph3
// {VMC0 (drains STG(t+1), ~3-phase flight), BARRIER, rd slice0 of t+1 from the
// just-proven slot, MFMA slice3, BARRIER}. Compiler emits the counted lgkm waits;
// SCHED0 pins phase boundaries; setprio(1) around each MFMA cluster.
// Swizzle (r5-verified, 0 conflicts): phys 16B-slot = logical ^ f(row),
// f(row)=(row^(row>>3))&7; staging source pre-permuted with same involution.
// Frag maps: A/B lane l: row/col = l&31, k = (l>>5)*8 + j.
// C/D (verified m74/m101): col = lane&31, row = (r&3) + 8*(r>>2) + 4*(lane>>5).
// MODE 0: bf16 out [row][col], +bias[col]
// MODE 1: bf16 out [col][row], +bias[col]   (transposed write, for V^T)
// MODE 2: bf16 out [row][col], *scale       (scores)
// MODE 3: f32  out [row][col]               (final output)
template <int MODE>
__global__ __launch_bounds__(512, 2) void gemm256_kernel(
    const unsigned short* __restrict__ Aall, const unsigned short* __restrict__ Ball,
    long long aBatch, long long bBatch, int K,
    const float* __restrict__ biasAll, long long biasBatch,
    void* __restrict__ outAll, long long outBatch, int ldOut, float scale,
    int gx, int gxy) {
  extern __shared__ char smem[];

  // XCD-aware bijective block swizzle (all grids have nwg % 8 == 0)
  const int nwg = (int)gridDim.x;
  const int lin = (int)blockIdx.x;
  int wg = (lin & 7) * (nwg >> 3) + (lin >> 3);
  const int z = wg / gxy; wg -= z * gxy;
  const int by = wg / gx;
  const int bx = wg - by * gx;
  const int bm = by * 256, bn = bx * 256;

  const unsigned short* A = Aall + (size_t)z * aBatch;
  const unsigned short* B = Ball + (size_t)z * bBatch;

  const int tid = threadIdx.x;           // 0..511
  const int lane = tid & 63, wid = tid >> 6;
  const int wr = wid >> 2, wc = wid & 3; // wave -> (2 x 4) output grid
  const int la31 = lane & 31, lg2 = lane >> 5;

  // ---- staging: per region 128 rows x 128 B; thread covers rows srow+{0,64,...}
  const int srow = tid >> 3;                                // 0..63
  const int sk = ((tid & 7) ^ ((srow ^ (srow >> 3)) & 7)) * 8;
  const unsigned short* aS0 = A + (size_t)(bm +   0 + srow) * K + sk;
  const unsigned short* aS1 = A + (size_t)(bm +  64 + srow) * K + sk;
  const unsigned short* aS2 = A + (size_t)(bm + 128 + srow) * K + sk;
  const unsigned short* aS3 = A + (size_t)(bm + 192 + srow) * K + sk;
  const unsigned short* bS0 = B + (size_t)(bn +   0 + srow) * K + sk;
  const unsigned short* bS1 = B + (size_t)(bn +  64 + srow) * K + sk;
  const unsigned short* bS2 = B + (size_t)(bn + 128 + srow) * K + sk;
  const unsigned short* bS3 = B + (size_t)(bn + 192 + srow) * K + sk;

// stage full K-tile tt (A 32KB @0, B 32KB @32768 within slot)
#define STG(tt)                                                           \
  do {                                                                    \
    char* _d = smem + (((tt) & 1) << 16) + tid * 16;                      \
    GLD16(aS0 + (size_t)(tt) * 64, _d);                                   \
    GLD16(aS1 + (size_t)(tt) * 64, _d + 8192);                            \
    GLD16(aS2 + (size_t)(tt) * 64, _d + 16384);                          \
    GLD16(aS3 + (size_t)(tt) * 64, _d + 24576);                          \
    GLD16(bS0 + (size_t)(tt) * 64, _d + 32768);                          \
    GLD16(bS1 + (size_t)(tt) * 64, _d + 40960);                          \
    GLD16(bS2 + (size_t)(tt) * 64, _d + 49152);                          \
    GLD16(bS3 + (size_t)(tt) * 64, _d + 57344);                          \
  } while (0)

  // ---- fragment read bases (row stride 128 B, XOR-swizzled 16B slots)
  int aO[4], aX[4];
#pragma unroll
  for (int m = 0; m < 4; ++m) {
    const int arow = wr * 128 + m * 32 + la31;
    aO[m] = arow * 128;
    aX[m] = (arow ^ (arow >> 3)) & 7;
  }
  int bO[2], bX[2];
#pragma unroll
  for (int n = 0; n < 2; ++n) {
    const int brow = wc * 64 + n * 32 + la31;
    bO[n] = 32768 + brow * 128;
    bX[n] = (brow ^ (brow >> 3)) & 7;
  }

#define RD_A(SET, BASE, KS)                                               \
  _Pragma("unroll") for (int m = 0; m < 4; ++m)                           \
    SET[m] = *(const short8*)((BASE) + aO[m] +                            \
                              (((((KS) << 1) + lg2) ^ aX[m]) << 4));
#define RD_B(SET, BASE, KS)                                               \
  _Pragma("unroll") for (int n = 0; n < 2; ++n)                           \
    SET[n] = *(const short8*)((BASE) + bO[n] +                            \
                              (((((KS) << 1) + lg2) ^ bX[n]) << 4));
#define MFMA_S(AV, BV)                                                    \
  __builtin_amdgcn_s_setprio(1);                                          \
  _Pragma("unroll") for (int m = 0; m < 4; ++m)                           \
  _Pragma("unroll") for (int n = 0; n < 2; ++n)                           \
    acc[m][n] = __builtin_amdgcn_mfma_f32_32x32x16_bf16(                  \
        AV[m], BV[n], acc[m][n], 0, 0, 0);                                \
  __builtin_amdgcn_s_setprio(0);

  f32x16 acc[4][2];
#pragma unroll
  for (int m = 0; m < 4; ++m)
#pragma unroll
    for (int n = 0; n < 2; ++n)
#pragma unroll
      for (int r = 0; r < 16; ++r) acc[m][n][r] = 0.f;

  const int NT = K >> 6;    // K-tiles of 64

  short8 avA[4], bvA[2], avB[4], bvB[2];

  // ---- prologue: stage tile 0; wait; read slice0 into set A
  STG(0);
  VMC0();
  BARRIER();
  RD_A(avA, smem, 0); RD_B(bvA, smem, 0);
  SCHED0();

  for (int t = 0; t < NT; ++t) {
    const char* base  = smem + ((t & 1) << 16);
    const char* nbase = smem + (((t + 1) & 1) << 16);

    // ph0: stage t+1 -> slot(t-1) [dead]; read slice1; MFMA slice0
    if (t + 1 < NT) STG(t + 1);
    RD_A(avB, base, 1); RD_B(bvB, base, 1);
    SCHED0();
    MFMA_S(avA, bvA);
    SCHED0();

    // ph1: read slice2; MFMA slice1
    RD_A(avA, base, 2); RD_B(bvA, base, 2);
    SCHED0();
    MFMA_S(avB, bvB);
    SCHED0();

    // ph2: read slice3; MFMA slice2
    RD_A(avB, base, 3); RD_B(bvB, base, 3);
    SCHED0();
    MFMA_S(avA, bvA);
    SCHED0();

    // ph3: prove STG(t+1) landed; read next tile slice0; MFMA slice3
    VMC0();
    BARRIER();
    if (t + 1 < NT) { RD_A(avA, nbase, 0); RD_B(bvA, nbase, 0); }
    SCHED0();
    MFMA_S(avB, bvB);
    SCHED0();
    BARRIER();
  }
#undef STG
#undef RD_A
#undef RD_B
#undef MFMA_S

  // ---- epilogue (C/D: col = lane&31, row = (r&3) + 8*(r>>2) + 4*(lane>>5))
  float bvv[2];
  if (MODE == 0 || MODE == 1) {
    const float* bias = biasAll + (size_t)z * biasBatch;
#pragma unroll
    for (int n = 0; n < 2; ++n) bvv[n] = bias[bn + wc * 64 + n * 32 + la31];
  }
#pragma unroll
  for (int m = 0; m < 4; ++m)
#pragma unroll
    for (int n = 0; n < 2; ++n)
#pragma unroll
      for (int r = 0; r < 16; ++r) {
        const int grow = bm + wr * 128 + m * 32 + (r & 3) + 8 * (r >> 2) + 4 * lg2;
        const int gcol = bn + wc * 64 + n * 32 + la31;
        float val = acc[m][n][r];
        if (MODE == 0 || MODE == 1) val += bvv[n];
        if (MODE == 2) val *= scale;
        if (MODE == 0 || MODE == 2) {
          unsigned short* o = (unsigned short*)outAll + (size_t)z * outBatch;
          o[(size_t)grow * ldOut + gcol] = f2bf(val);
        } else if (MODE == 1) {
          unsigned short* o = (unsigned short*)outAll + (size_t)z * outBatch;
          o[(size_t)gcol * ldOut + grow] = f2bf(val);
        } else {
          float* o = (float*)outAll + (size_t)z * outBatch;
          o[(size_t)grow * ldOut + gcol] = val;
        }
      }
}

// ---------------- row softmax, in place on bf16 [nrows][SEQ] ----------------
__global__ __launch_bounds__(256) void softmax_kernel(unsigned short* __restrict__ Sb) {
  const size_t row = blockIdx.x;
  unsigned short* p = Sb + row * (size_t)SEQ;
  const int tid = threadIdx.x;
  const int lane = tid & 63, wid = tid >> 6;
  float v[16];
  const short8 u0 = *(const short8*)&p[tid * 16];
  const short8 u1 = *(const short8*)&p[tid * 16 + 8];
#pragma unroll
  for (int j = 0; j < 8; ++j) v[j] = bf2f((unsigned short)u0[j]);
#pragma unroll
  for (int j = 0; j < 8; ++j) v[8 + j] = bf2f((unsigned short)u1[j]);
  float mx = v[0];
#pragma unroll
  for (int j = 1; j < 16; ++j) mx = fmaxf(mx, v[j]);
#pragma unroll
  for (int off = 32; off; off >>= 1) mx = fmaxf(mx, __shfl_xor(mx, off));
  __shared__ float red[8];
  if (lane == 0) red[wid] = mx;
  __syncthreads();
  mx = fmaxf(fmaxf(red[0], red[1]), fmaxf(red[2], red[3]));
  float s = 0.f;
#pragma unroll
  for (int j = 0; j < 16; ++j) { v[j] = __expf(v[j] - mx); s += v[j]; }
#pragma unroll
  for (int off = 32; off; off >>= 1) s += __shfl_xor(s, off);
  if (lane == 0) red[4 + wid] = s;
  __syncthreads();
  s = (red[4] + red[5]) + (red[6] + red[7]);
  const float inv = 1.0f / s;
  short8 o0, o1;
#pragma unroll
  for (int j = 0; j < 8; ++j) o0[j] = (short)f2bf(v[j] * inv);
#pragma unroll
  for (int j = 0; j < 8; ++j) o1[j] = (short)f2bf(v[8 + j] * inv);
  *(short8*)&p[tid * 16] = o0;
  *(short8*)&p[tid * 16 + 8] = o1;
}

extern "C" void kernel_launch(void* const* d_in, const int* in_sizes, int n_in,
                              void* d_out, int out_size, void* d_ws, size_t ws_size,
                              hipStream_t stream) {
  const float* h  = (const float*)d_in[0];
  const float* Wq = (const float*)d_in[1];
  const float* bq = (const float*)d_in[2];
  const float* Wk = (const float*)d_in[3];
  const float* bk = (const float*)d_in[4];
  const float* Wv = (const float*)d_in[5];
  const float* bv = (const float*)d_in[6];
  float* out = (float*)d_out;
  char* ws = (char*)d_ws;

  // allow 128KB dynamic LDS for the GEMM kernels (idempotent, not a stream op)
  (void)hipFuncSetAttribute((const void*)&gemm256_kernel<0>,
                            hipFuncAttributeMaxDynamicSharedMemorySize, 131072);
  (void)hipFuncSetAttribute((const void*)&gemm256_kernel<1>,
                            hipFuncAttributeMaxDynamicSharedMemorySize, 131072);
  (void)hipFuncSetAttribute((const void*)&gemm256_kernel<2>,
                            hipFuncAttributeMaxDynamicSharedMemorySize, 131072);
  (void)hipFuncSetAttribute((const void*)&gemm256_kernel<3>,
                            hipFuncAttributeMaxDynamicSharedMemorySize, 131072);

  // ws layout (224 MB):
  //  [0,32MB)    h_bf16 [S][HID]          -- dead after projections
  //  [32,128MB)  Wt bf16 [12][E][HID]     -- dead after projections
  //  [0,128MB)   Sb bf16 [H][S][S]        -- scores/probs (reuses the two above)
  //  [128,160)   Qb bf16 [H][S][E]
  //  [160,192)   Kb bf16 [H][S][E]
  //  [192,224)   Vt bf16 [H][E][S]
  unsigned short* hB = (unsigned short*)ws;
  unsigned short* wt = (unsigned short*)(ws + (32ull << 20));
  unsigned short* Sb = (unsigned short*)ws;
  unsigned short* Qb = (unsigned short*)(ws + (128ull << 20));
  unsigned short* Kb = (unsigned short*)(ws + (160ull << 20));
  unsigned short* Vt = (unsigned short*)(ws + (192ull << 20));

  const long long WED = (long long)EDIM * HID;   // per-(mat,head) Wt elems
  const long long QKB = (long long)SEQ * EDIM;   // per-head Q/K elems
  const long long SSB = (long long)SEQ * SEQ;    // per-head score elems

  hconv_kernel<<<dim3((SEQ * (size_t)HID) / (256 * 8)), 256, 0, stream>>>(h, hB);
  wconv_kernel<<<dim3((HID / 64) * (EDIM / 64), 12), 256, 0, stream>>>(Wq, Wk, Wv, wt);

  // Projections: M=S=4096, N=E=1024, K=HID  -> grid (4 x 16 x 4) = 256 blocks, 1-D
  gemm256_kernel<0><<<dim3(4 * 16 * 4), 512, 131072, stream>>>(
      hB, wt + 0 * WED, 0, WED, HID, bq, EDIM, Qb, QKB, EDIM, 1.f, 4, 64);
  gemm256_kernel<0><<<dim3(4 * 16 * 4), 512, 131072, stream>>>(
      hB, wt + 4 * WED, 0, WED, HID, bk, EDIM, Kb, QKB, EDIM, 1.f, 4, 64);
  gemm256_kernel<1><<<dim3(4 * 16 * 4), 512, 131072, stream>>>(
      hB, wt + 8 * WED, 0, WED, HID, bv, EDIM, Vt, QKB, SEQ, 1.f, 4, 64);

  // Scores: S = Q K^T / 32   (M=N=S, K=E) -> grid (16 x 16 x 4) = 1024 blocks
  gemm256_kernel<2><<<dim3(16 * 16 * 4), 512, 131072, stream>>>(
      Qb, Kb, QKB, QKB, EDIM, nullptr, 0, Sb, SSB, SEQ, 0.03125f, 16, 256);

  // Softmax over rows, in place
  softmax_kernel<<<dim3(NHEAD * SEQ), 256, 0, stream>>>(Sb);

  // Out: O = P V  (M=S, N=E, K=S), written to out[s][head*E + e] as f32
  gemm256_kernel<3><<<dim3(4 * 16 * 4), 512, 131072, stream>>>(
      Sb, Vt, SSB, QKB, SEQ, nullptr, 0, out, (long long)EDIM, NHEAD * EDIM, 1.f, 4, 64);
}